// Round 1
// baseline (4993.997 us; speedup 1.0000x reference)
//
#include <hip/hip_runtime.h>
#include <stdint.h>

#define T_STEPS 599   // T-1 scan steps (x[1:])
#define T_RAW   600
#define NIN     16384
#define N0      4096
#define N1      1024

// ---- workspace layout (bytes) ----
// I0T   : [599][4096] float   (time-major so LIF-0 reads coalesced)
// S0bits: [4096][20]  u32     (bitpacked spikes, 599 bits/row)
// I1    : [1024][600] float
// S1bits: [1024][20]  u32
static const size_t OFF_I0T = 0;
static const size_t SZ_I0T  = (size_t)T_STEPS * N0 * 4;      // 9,814,016
static const size_t OFF_S0B = OFF_I0T + SZ_I0T;
static const size_t SZ_S0B  = (size_t)N0 * 20 * 4;           // 327,680
static const size_t OFF_I1  = OFF_S0B + SZ_S0B;
static const size_t SZ_I1   = (size_t)N1 * T_RAW * 4;        // 2,457,600
static const size_t OFF_S1B = OFF_I1 + SZ_I1;                // total ~12.1 MiB

// ============ Kernel 1: I0 = W0 @ X, fp64 accumulate ============
// A = W0 (4096 x 16384) row-major, B[i][tau] = stim[i*600 + tau + 1]
// C stored time-major: I0T[tau*4096 + n]
__global__ __launch_bounds__(256) void gemm_i0(const float* __restrict__ W0,
                                               const float* __restrict__ stim,
                                               float* __restrict__ I0T) {
    __shared__ double As[64][33];   // [n][k], padded
    __shared__ double Bs[32][64];   // [k][tau]
    const int tid = threadIdx.x;
    const int tx = tid & 15;        // tau direction
    const int ty = tid >> 4;        // n direction
    const int n0   = blockIdx.y * 64;
    const int tau0 = blockIdx.x * 64;

    double acc[4][4];
#pragma unroll
    for (int m = 0; m < 4; ++m)
#pragma unroll
        for (int n = 0; n < 4; ++n) acc[m][n] = 0.0;

    for (int k0 = 0; k0 < NIN; k0 += 32) {
        // stage A tile (64x32) as double
        {
            const int r  = tid >> 3;        // 0..31
            const int c4 = (tid & 7) * 4;   // 0..28
            float4 v0 = *reinterpret_cast<const float4*>(&W0[(size_t)(n0 + r) * NIN + k0 + c4]);
            As[r][c4 + 0] = (double)v0.x; As[r][c4 + 1] = (double)v0.y;
            As[r][c4 + 2] = (double)v0.z; As[r][c4 + 3] = (double)v0.w;
            float4 v1 = *reinterpret_cast<const float4*>(&W0[(size_t)(n0 + r + 32) * NIN + k0 + c4]);
            As[r + 32][c4 + 0] = (double)v1.x; As[r + 32][c4 + 1] = (double)v1.y;
            As[r + 32][c4 + 2] = (double)v1.z; As[r + 32][c4 + 3] = (double)v1.w;
        }
        // stage B tile (32x64) as double; guard tau
        {
            const int tc  = tid & 63;
            const int r0  = tid >> 6;       // 0..3
            const int taug = tau0 + tc;
            const bool valid = (taug < T_STEPS);
#pragma unroll
            for (int rr = 0; rr < 8; ++rr) {
                const int r = r0 + rr * 4;
                float v = valid ? stim[(size_t)(k0 + r) * T_RAW + taug + 1] : 0.0f;
                Bs[r][tc] = (double)v;
            }
        }
        __syncthreads();
#pragma unroll
        for (int kk = 0; kk < 32; ++kk) {
            double a0 = As[ty * 4 + 0][kk];
            double a1 = As[ty * 4 + 1][kk];
            double a2 = As[ty * 4 + 2][kk];
            double a3 = As[ty * 4 + 3][kk];
            double b0 = Bs[kk][tx * 4 + 0];
            double b1 = Bs[kk][tx * 4 + 1];
            double b2 = Bs[kk][tx * 4 + 2];
            double b3 = Bs[kk][tx * 4 + 3];
            acc[0][0] = fma(a0, b0, acc[0][0]); acc[0][1] = fma(a0, b1, acc[0][1]);
            acc[0][2] = fma(a0, b2, acc[0][2]); acc[0][3] = fma(a0, b3, acc[0][3]);
            acc[1][0] = fma(a1, b0, acc[1][0]); acc[1][1] = fma(a1, b1, acc[1][1]);
            acc[1][2] = fma(a1, b2, acc[1][2]); acc[1][3] = fma(a1, b3, acc[1][3]);
            acc[2][0] = fma(a2, b0, acc[2][0]); acc[2][1] = fma(a2, b1, acc[2][1]);
            acc[2][2] = fma(a2, b2, acc[2][2]); acc[2][3] = fma(a2, b3, acc[2][3]);
            acc[3][0] = fma(a3, b0, acc[3][0]); acc[3][1] = fma(a3, b1, acc[3][1]);
            acc[3][2] = fma(a3, b2, acc[3][2]); acc[3][3] = fma(a3, b3, acc[3][3]);
        }
        __syncthreads();
    }
    // store: C[tau][n], n block of 4 contiguous -> float4
    const int nb = n0 + ty * 4;
#pragma unroll
    for (int nn = 0; nn < 4; ++nn) {
        const int taug = tau0 + tx * 4 + nn;
        if (taug < T_STEPS) {
            float4 o;
            o.x = (float)acc[0][nn]; o.y = (float)acc[1][nn];
            o.z = (float)acc[2][nn]; o.w = (float)acc[3][nn];
            *reinterpret_cast<float4*>(&I0T[(size_t)taug * N0 + nb]) = o;
        }
    }
}

// ============ Kernel 2: layer-0 LIF scan -> bitpacked S0 ============
__global__ void lif0(const float* __restrict__ I0T, uint32_t* __restrict__ S0bits) {
#pragma clang fp contract(off)
    const int n = blockIdx.x * 256 + threadIdx.x;   // 0..4095
    float v = 0.0f;
    uint32_t word = 0;
    for (int t = 0; t < T_STEPS; ++t) {
        float I = I0T[(size_t)t * N0 + n];
        float a = v * 0.9f;        // separate rounding (match jnp: mul then add)
        v = a + I;
        if (v >= 1.0f) { word |= (1u << (t & 31)); v = 0.0f; }
        if ((t & 31) == 31) { S0bits[n * 20 + (t >> 5)] = word; word = 0; }
    }
    S0bits[n * 20 + (T_STEPS >> 5)] = word;  // flush bits 576..598 (word 18)
}

// ============ Kernel 3: I1[j][t] = sum_i W1[j,i]*S0[i, t-d(j,i)] ============
// one block per output neuron j; W1 row + delay row staged in LDS;
// S0 read as bits (327 KB total -> L2 resident)
__global__ __launch_bounds__(256) void gather_i1(const float* __restrict__ W1,
                                                 const int* __restrict__ delays,
                                                 const uint32_t* __restrict__ S0bits,
                                                 float* __restrict__ I1) {
    __shared__ double  wl[N0];   // 32 KB
    __shared__ uint8_t dl[N0];   // 4 KB
    const int j   = blockIdx.x;
    const int tid = threadIdx.x;
    for (int i = tid; i < N0; i += 256) {
        wl[i] = (double)W1[(size_t)j * N0 + i];
        dl[i] = (uint8_t)delays[(size_t)j * N0 + i];
    }
    __syncthreads();
    const int t0 = tid, t1 = tid + 256, t2 = tid + 512;
    const bool has2 = (t2 < T_STEPS);
    double a0 = 0.0, a1 = 0.0, a2 = 0.0;
    for (int i = 0; i < N0; ++i) {
        const int d = (int)dl[i];
        const double w = wl[i];
        const uint32_t* row = S0bits + i * 20;
        const int s0i = t0 - d;                     // may be <0 (pre-history = 0)
        if (s0i >= 0 && ((row[s0i >> 5] >> (s0i & 31)) & 1u)) a0 += w;
        const int s1i = t1 - d;                     // always in [241, 511]
        if ((row[s1i >> 5] >> (s1i & 31)) & 1u) a1 += w;
        if (has2) {
            const int s2i = t2 - d;                 // in [497, 598]
            if ((row[s2i >> 5] >> (s2i & 31)) & 1u) a2 += w;
        }
    }
    I1[(size_t)j * T_RAW + t0] = (float)a0;
    I1[(size_t)j * T_RAW + t1] = (float)a1;
    if (has2) I1[(size_t)j * T_RAW + t2] = (float)a2;
}

// ============ Kernel 4: layer-1 LIF scan -> bitpacked S1 ============
__global__ void lif1(const float* __restrict__ I1, uint32_t* __restrict__ S1bits) {
#pragma clang fp contract(off)
    const int j = blockIdx.x * 256 + threadIdx.x;   // 0..1023
    float v = 0.0f;
    uint32_t word = 0;
    for (int t = 0; t < T_STEPS; ++t) {
        float I = I1[(size_t)j * T_RAW + t];
        float a = v * 0.9f;
        v = a + I;
        if (v >= 1.0f) { word |= (1u << (t & 31)); v = 0.0f; }
        if ((t & 31) == 31) { S1bits[j * 20 + (t >> 5)] = word; word = 0; }
    }
    S1bits[j * 20 + (T_STEPS >> 5)] = word;
}

// ============ Kernel 5: expand bits -> fp32 outputs (S0.T, S1.T) ============
__global__ void expand_out(const uint32_t* __restrict__ S0bits,
                           const uint32_t* __restrict__ S1bits,
                           float* __restrict__ out) {
    const int t = blockIdx.x * 256 + threadIdx.x;
    if (t >= T_STEPS) return;
    const int row = blockIdx.y;
    if (row < N0) {
        uint32_t b = (S0bits[row * 20 + (t >> 5)] >> (t & 31)) & 1u;
        out[(size_t)row * T_STEPS + t] = (float)b;
    } else {
        const int jj = row - N0;
        uint32_t b = (S1bits[jj * 20 + (t >> 5)] >> (t & 31)) & 1u;
        out[(size_t)N0 * T_STEPS + (size_t)jj * T_STEPS + t] = (float)b;
    }
}

extern "C" void kernel_launch(void* const* d_in, const int* in_sizes, int n_in,
                              void* d_out, int out_size, void* d_ws, size_t ws_size,
                              hipStream_t stream) {
    const float* stim   = (const float*)d_in[0];   // 128*128*600
    const float* W0     = (const float*)d_in[1];   // 4096*16384
    const float* W1     = (const float*)d_in[2];   // 1024*4096
    const int*   delays = (const int*)d_in[3];     // 1024*4096

    char* ws = (char*)d_ws;
    float*    I0T  = (float*)(ws + OFF_I0T);
    uint32_t* S0b  = (uint32_t*)(ws + OFF_S0B);
    float*    I1   = (float*)(ws + OFF_I1);
    uint32_t* S1b  = (uint32_t*)(ws + OFF_S1B);
    float*    out  = (float*)d_out;

    hipLaunchKernelGGL(gemm_i0,   dim3(10, 64), dim3(256), 0, stream, W0, stim, I0T);
    hipLaunchKernelGGL(lif0,      dim3(16),     dim3(256), 0, stream, I0T, S0b);
    hipLaunchKernelGGL(gather_i1, dim3(1024),   dim3(256), 0, stream, W1, delays, S0b, I1);
    hipLaunchKernelGGL(lif1,      dim3(4),      dim3(256), 0, stream, I1, S1b);
    hipLaunchKernelGGL(expand_out, dim3(3, N0 + N1), dim3(256), 0, stream, S0b, S1b, out);
}

// Round 3
// 3469.766 us; speedup vs baseline: 1.4393x; 1.4393x over previous
//
#include <hip/hip_runtime.h>
#include <stdint.h>

#define T_STEPS 599   // T-1 scan steps (x[1:])
#define T_RAW   600
#define NIN     16384
#define N0      4096
#define N1      1024

typedef double d4 __attribute__((ext_vector_type(4)));

// ---- workspace layout (bytes) ----
static const size_t OFF_I0T = 0;
static const size_t SZ_I0T  = (size_t)T_STEPS * N0 * 4;      // 9,814,016
static const size_t OFF_S0B = OFF_I0T + SZ_I0T;
static const size_t SZ_S0B  = (size_t)N0 * 20 * 4;           // 327,680
static const size_t OFF_I1  = OFF_S0B + SZ_S0B;
static const size_t SZ_I1   = (size_t)N1 * T_RAW * 4;        // 2,457,600
static const size_t OFF_S1B = OFF_I1 + SZ_I1;                // total ~12.1 MiB

// ============ Kernel 1: I0 = W0 @ X via fp64 MFMA, probed C-layout ============
// C[n][tau]: M=4096 (n), N=599 (tau), K=16384. Block tile 32(M) x 64(N),
// 4 waves each own a 32x16 tau-slab. K-chunk 64. fp32 LDS, f64 in-register.
// A frag: lane holds A[l&15][l>>4]; B frag: B[l>>4][l&15] (universal CDNA
// 16x16 input pattern). C/D reg->(row,col) mapping derived at runtime by
// two probe MFMAs (layout-agnostic store).
__global__ __launch_bounds__(256) void gemm_i0_mfma(const float* __restrict__ W0,
                                                    const float* __restrict__ stim,
                                                    float* __restrict__ I0T) {
    __shared__ float As[32 * 68];   // [row][k], pad 68
    __shared__ float Bs[64 * 68];   // [k][tau]
    const int tid  = threadIdx.x;
    const int lane = tid & 63;
    const int wid  = tid >> 6;          // wave id 0..3 -> 16-wide tau slab
    const int n0   = blockIdx.y * 32;
    const int tau0 = blockIdx.x * 64;
    const int r15  = lane & 15;
    const int c    = lane >> 4;         // k-phase 0..3

    // ---- probe the C/D layout of v_mfma_f64_16x16x4f64 ----
    // A[i][0]=1, B[0][j]=j  ->  D[i][j] = j   (reg value = its column)
    // A[i][0]=i, B[0][j]=1  ->  D[i][j] = i   (reg value = its row)
    d4 zero = {0.0, 0.0, 0.0, 0.0};
    const double ap1 = (c == 0) ? 1.0 : 0.0;
    const double bp1 = (c == 0) ? (double)r15 : 0.0;
    d4 pcol = __builtin_amdgcn_mfma_f64_16x16x4f64(ap1, bp1, zero, 0, 0, 0);
    const double ap2 = (c == 0) ? (double)r15 : 0.0;
    const double bp2 = (c == 0) ? 1.0 : 0.0;
    d4 prow = __builtin_amdgcn_mfma_f64_16x16x4f64(ap2, bp2, zero, 0, 0, 0);
    int rowr[4], colr[4];
#pragma unroll
    for (int r = 0; r < 4; ++r) {
        int cc = (int)pcol[r]; cc = cc < 0 ? 0 : (cc > 15 ? 15 : cc);
        int rw = (int)prow[r]; rw = rw < 0 ? 0 : (rw > 15 ? 15 : rw);
        colr[r] = cc; rowr[r] = rw;
    }

    d4 acc0 = {0.0, 0.0, 0.0, 0.0};    // C rows n0..n0+15
    d4 acc1 = {0.0, 0.0, 0.0, 0.0};    // C rows n0+16..n0+31

    for (int k0 = 0; k0 < NIN; k0 += 64) {
        // stage A: 32 rows x 64 k = 512 float4, 2 per thread
#pragma unroll
        for (int p = 0; p < 2; ++p) {
            const int q  = tid + p * 256;
            const int r  = q >> 4;          // 0..31
            const int kq = q & 15;          // float4 col
            const float4 v = *reinterpret_cast<const float4*>(
                &W0[(size_t)(n0 + r) * NIN + k0 + 4 * kq]);
            *reinterpret_cast<float4*>(&As[r * 68 + 4 * kq]) = v;
        }
        // stage B: 64 k x 64 tau; scalar guarded loads (stim col +1 offset)
#pragma unroll
        for (int p = 0; p < 4; ++p) {
            const int q  = tid + p * 256;
            const int kl = q >> 4;          // 0..63
            const int tq = q & 15;
            const size_t rowb = (size_t)(k0 + kl) * T_RAW;
            const int t0g = tau0 + 4 * tq;
            float4 v;
            v.x = (t0g + 0 < T_STEPS) ? stim[rowb + t0g + 1] : 0.0f;
            v.y = (t0g + 1 < T_STEPS) ? stim[rowb + t0g + 2] : 0.0f;
            v.z = (t0g + 2 < T_STEPS) ? stim[rowb + t0g + 3] : 0.0f;
            v.w = (t0g + 3 < T_STEPS) ? stim[rowb + t0g + 4] : 0.0f;
            *reinterpret_cast<float4*>(&Bs[kl * 68 + 4 * tq]) = v;
        }
        __syncthreads();
#pragma unroll
        for (int s = 0; s < 16; ++s) {
            const int k = 4 * s + c;
            const double a0 = (double)As[r15 * 68 + k];
            const double a1 = (double)As[(16 + r15) * 68 + k];
            const double b  = (double)Bs[k * 68 + wid * 16 + r15];
            acc0 = __builtin_amdgcn_mfma_f64_16x16x4f64(a0, b, acc0, 0, 0, 0);
            acc1 = __builtin_amdgcn_mfma_f64_16x16x4f64(a1, b, acc1, 0, 0, 0);
        }
        __syncthreads();
    }
    // store C[n][tau] -> I0T[tau*4096 + n] as fp32, probed (row,col) per reg
#pragma unroll
    for (int r = 0; r < 4; ++r) {
        const int tcol = tau0 + wid * 16 + colr[r];
        if (tcol < T_STEPS) {
            I0T[(size_t)tcol * N0 + n0 + rowr[r]]      = (float)acc0[r];
            I0T[(size_t)tcol * N0 + n0 + 16 + rowr[r]] = (float)acc1[r];
        }
    }
}

// ============ Kernel 2: layer-0 LIF scan -> bitpacked S0 ============
__global__ void lif0(const float* __restrict__ I0T, uint32_t* __restrict__ S0bits) {
#pragma clang fp contract(off)
    const int n = blockIdx.x * 256 + threadIdx.x;   // 0..4095
    float v = 0.0f;
    uint32_t word = 0;
    for (int t = 0; t < T_STEPS; ++t) {
        float I = I0T[(size_t)t * N0 + n];
        float a = v * 0.9f;        // separate rounding (match jnp: mul then add)
        v = a + I;
        if (v >= 1.0f) { word |= (1u << (t & 31)); v = 0.0f; }
        if ((t & 31) == 31) { S0bits[n * 20 + (t >> 5)] = word; word = 0; }
    }
    S0bits[n * 20 + (T_STEPS >> 5)] = word;  // flush bits 576..598
}

// ============ Kernel 3: I1[j][t] = sum_i W1[j,i]*S0[i, t-d(j,i)] ============
__global__ __launch_bounds__(256) void gather_i1(const float* __restrict__ W1,
                                                 const int* __restrict__ delays,
                                                 const uint32_t* __restrict__ S0bits,
                                                 float* __restrict__ I1) {
    __shared__ double  wl[N0];   // 32 KB
    __shared__ uint8_t dl[N0];   // 4 KB
    const int j   = blockIdx.x;
    const int tid = threadIdx.x;
    for (int i = tid; i < N0; i += 256) {
        wl[i] = (double)W1[(size_t)j * N0 + i];
        dl[i] = (uint8_t)delays[(size_t)j * N0 + i];
    }
    __syncthreads();
    const int t0 = tid, t1 = tid + 256, t2 = tid + 512;
    const bool has2 = (t2 < T_STEPS);
    double a0 = 0.0, a1 = 0.0, a2 = 0.0;
    for (int i = 0; i < N0; ++i) {
        const int d = (int)dl[i];
        const double w = wl[i];
        const uint32_t* row = S0bits + i * 20;
        const int s0i = t0 - d;
        if (s0i >= 0 && ((row[s0i >> 5] >> (s0i & 31)) & 1u)) a0 += w;
        const int s1i = t1 - d;
        if ((row[s1i >> 5] >> (s1i & 31)) & 1u) a1 += w;
        if (has2) {
            const int s2i = t2 - d;
            if ((row[s2i >> 5] >> (s2i & 31)) & 1u) a2 += w;
        }
    }
    I1[(size_t)j * T_RAW + t0] = (float)a0;
    I1[(size_t)j * T_RAW + t1] = (float)a1;
    if (has2) I1[(size_t)j * T_RAW + t2] = (float)a2;
}

// ============ Kernel 4: layer-1 LIF scan -> bitpacked S1 ============
__global__ void lif1(const float* __restrict__ I1, uint32_t* __restrict__ S1bits) {
#pragma clang fp contract(off)
    const int j = blockIdx.x * 256 + threadIdx.x;   // 0..1023
    float v = 0.0f;
    uint32_t word = 0;
    for (int t = 0; t < T_STEPS; ++t) {
        float I = I1[(size_t)j * T_RAW + t];
        float a = v * 0.9f;
        v = a + I;
        if (v >= 1.0f) { word |= (1u << (t & 31)); v = 0.0f; }
        if ((t & 31) == 31) { S1bits[j * 20 + (t >> 5)] = word; word = 0; }
    }
    S1bits[j * 20 + (T_STEPS >> 5)] = word;
}

// ============ Kernel 5: expand bits -> fp32 outputs (S0.T, S1.T) ============
__global__ void expand_out(const uint32_t* __restrict__ S0bits,
                           const uint32_t* __restrict__ S1bits,
                           float* __restrict__ out) {
    const int t = blockIdx.x * 256 + threadIdx.x;
    if (t >= T_STEPS) return;
    const int row = blockIdx.y;
    if (row < N0) {
        uint32_t b = (S0bits[row * 20 + (t >> 5)] >> (t & 31)) & 1u;
        out[(size_t)row * T_STEPS + t] = (float)b;
    } else {
        const int jj = row - N0;
        uint32_t b = (S1bits[jj * 20 + (t >> 5)] >> (t & 31)) & 1u;
        out[(size_t)N0 * T_STEPS + (size_t)jj * T_STEPS + t] = (float)b;
    }
}

extern "C" void kernel_launch(void* const* d_in, const int* in_sizes, int n_in,
                              void* d_out, int out_size, void* d_ws, size_t ws_size,
                              hipStream_t stream) {
    const float* stim   = (const float*)d_in[0];   // 128*128*600
    const float* W0     = (const float*)d_in[1];   // 4096*16384
    const float* W1     = (const float*)d_in[2];   // 1024*4096
    const int*   delays = (const int*)d_in[3];     // 1024*4096

    char* ws = (char*)d_ws;
    float*    I0T  = (float*)(ws + OFF_I0T);
    uint32_t* S0b  = (uint32_t*)(ws + OFF_S0B);
    float*    I1   = (float*)(ws + OFF_I1);
    uint32_t* S1b  = (uint32_t*)(ws + OFF_S1B);
    float*    out  = (float*)d_out;

    hipLaunchKernelGGL(gemm_i0_mfma, dim3(10, 128), dim3(256), 0, stream, W0, stim, I0T);
    hipLaunchKernelGGL(lif0,         dim3(16),      dim3(256), 0, stream, I0T, S0b);
    hipLaunchKernelGGL(gather_i1,    dim3(1024),    dim3(256), 0, stream, W1, delays, S0b, I1);
    hipLaunchKernelGGL(lif1,         dim3(4),       dim3(256), 0, stream, I1, S1b);
    hipLaunchKernelGGL(expand_out,   dim3(3, N0 + N1), dim3(256), 0, stream, S0b, S1b, out);
}

// Round 4
// 3417.036 us; speedup vs baseline: 1.4615x; 1.0154x over previous
//
#include <hip/hip_runtime.h>
#include <stdint.h>

#define T_STEPS 599   // T-1 scan steps (x[1:])
#define T_RAW   600
#define NIN     16384
#define N0      4096
#define N1      1024

typedef double d4 __attribute__((ext_vector_type(4)));

// ---- workspace layout (bytes) ----
static const size_t OFF_I0T = 0;
static const size_t SZ_I0T  = (size_t)T_STEPS * N0 * 4;      // 9,814,016
static const size_t OFF_S0B = OFF_I0T + SZ_I0T;
static const size_t SZ_S0B  = (size_t)N0 * 20 * 4;           // 327,680
static const size_t OFF_I1  = OFF_S0B + SZ_S0B;
static const size_t SZ_I1   = (size_t)N1 * T_RAW * 4;        // 2,457,600
static const size_t OFF_S1B = OFF_I1 + SZ_I1;                // total ~12.1 MiB

// ============ Kernel 1: I0 = W0 @ X via fp64 MFMA, double-buffered ============
// C[n][tau]: M=4096 (n), N=599 (tau), K=16384. Block tile 32(M) x 64(N),
// 4 waves each own a 32x16 tau-slab. K-chunk 64. fp32 LDS (2 buffers),
// f64 in-register. A frag: lane holds A[l&15][l>>4]; B frag: B[l>>4][l&15].
// C/D reg->(row,col) probed at runtime (2 cheap MFMAs) — proven in R3.
// Pipeline per chunk: ds_write(regs) -> barrier -> issue next loads -> MFMA.
// vmcnt is 0 at the barrier (loads consumed by ds_write), so the compiler's
// auto vmcnt-drain there is free; new loads hide under the MFMA phase.
__global__ __launch_bounds__(256) void gemm_i0_mfma(const float* __restrict__ W0,
                                                    const float* __restrict__ stim,
                                                    float* __restrict__ I0T) {
    __shared__ float As[2][32 * 68];   // [buf][row*68 + k], pad 68
    __shared__ float Bs[2][64 * 68];   // [buf][k*68 + tau]
    const int tid  = threadIdx.x;
    const int lane = tid & 63;
    const int wid  = tid >> 6;          // wave id 0..3 -> 16-wide tau slab
    const int n0   = blockIdx.y * 32;
    const int tau0 = blockIdx.x * 64;
    const int r15  = lane & 15;
    const int c    = lane >> 4;         // k-phase 0..3

    // ---- probe the C/D layout of v_mfma_f64_16x16x4f64 (proven R3) ----
    d4 zero = {0.0, 0.0, 0.0, 0.0};
    const double ap1 = (c == 0) ? 1.0 : 0.0;
    const double bp1 = (c == 0) ? (double)r15 : 0.0;
    d4 pcol = __builtin_amdgcn_mfma_f64_16x16x4f64(ap1, bp1, zero, 0, 0, 0);
    const double ap2 = (c == 0) ? (double)r15 : 0.0;
    const double bp2 = (c == 0) ? 1.0 : 0.0;
    d4 prow = __builtin_amdgcn_mfma_f64_16x16x4f64(ap2, bp2, zero, 0, 0, 0);
    int rowr[4], colr[4];
#pragma unroll
    for (int r = 0; r < 4; ++r) {
        int cc = (int)pcol[r]; cc = cc < 0 ? 0 : (cc > 15 ? 15 : cc);
        int rw = (int)prow[r]; rw = rw < 0 ? 0 : (rw > 15 ? 15 : rw);
        colr[r] = cc; rowr[r] = rw;
    }

    // ---- staging thread mapping (identical math to R3) ----
    const int sr  = tid >> 4;          // 0..15
    const int sc4 = (tid & 15) * 4;    // float4 column (A: k, B: tau)
    const int t0g = tau0 + sc4;        // B tau base for this thread
    // A: rows sr, sr+16; k offset sc4. B: k rows sr+16p (p=0..3), taus t0g..t0g+3
    const float* aPtr0 = W0 + (size_t)(n0 + sr) * NIN + sc4;
    const float* aPtr1 = W0 + (size_t)(n0 + sr + 16) * NIN + sc4;
    const float* bPtrs[4];
#pragma unroll
    for (int p = 0; p < 4; ++p)
        bPtrs[p] = stim + (size_t)(sr + 16 * p) * T_RAW + t0g;
    // fast path: all 4 B values valid and float4 at t0g is in-bounds
    const bool fastB = (tau0 + 68) <= T_RAW;   // blocks 0..8 fast, block 9 slow

    float4 aReg[2];
    float4 bReg[4];

    auto loadChunk = [&]() {
        aReg[0] = *reinterpret_cast<const float4*>(aPtr0);
        aReg[1] = *reinterpret_cast<const float4*>(aPtr1);
        if (fastB) {
#pragma unroll
            for (int p = 0; p < 4; ++p) {
                const float4 f = *reinterpret_cast<const float4*>(bPtrs[p]);
                const float  e = bPtrs[p][4];
                bReg[p].x = f.y; bReg[p].y = f.z; bReg[p].z = f.w; bReg[p].w = e;
            }
        } else {
#pragma unroll
            for (int p = 0; p < 4; ++p) {
                const float* bp = bPtrs[p];
                bReg[p].x = (t0g + 0 < T_STEPS) ? bp[1] : 0.0f;
                bReg[p].y = (t0g + 1 < T_STEPS) ? bp[2] : 0.0f;
                bReg[p].z = (t0g + 2 < T_STEPS) ? bp[3] : 0.0f;
                bReg[p].w = (t0g + 3 < T_STEPS) ? bp[4] : 0.0f;
            }
        }
        aPtr0 += 64; aPtr1 += 64;
#pragma unroll
        for (int p = 0; p < 4; ++p) bPtrs[p] += 64 * T_RAW;
    };

    d4 acc0 = {0.0, 0.0, 0.0, 0.0};    // C rows n0..n0+15
    d4 acc1 = {0.0, 0.0, 0.0, 0.0};    // C rows n0+16..n0+31

    loadChunk();                        // prologue: chunk 0 -> regs
    int cur = 0;

    for (int ch = 0; ch < NIN / 64; ++ch) {
        // write staged regs -> buf[cur]
        float* Aw = &As[cur][0];
        float* Bw = &Bs[cur][0];
        *reinterpret_cast<float4*>(&Aw[sr * 68 + sc4])        = aReg[0];
        *reinterpret_cast<float4*>(&Aw[(sr + 16) * 68 + sc4]) = aReg[1];
#pragma unroll
        for (int p = 0; p < 4; ++p)
            *reinterpret_cast<float4*>(&Bw[(sr + 16 * p) * 68 + sc4]) = bReg[p];
        __syncthreads();               // vmcnt already 0 here -> free drain

        if (ch + 1 < NIN / 64) loadChunk();   // issue next chunk's loads

        const float* Ar = &As[cur][0];
        const float* Br = &Bs[cur][0];
#pragma unroll
        for (int s = 0; s < 16; ++s) {
            const int k = 4 * s + c;
            const double a0 = (double)Ar[r15 * 68 + k];
            const double a1 = (double)Ar[(16 + r15) * 68 + k];
            const double b  = (double)Br[k * 68 + wid * 16 + r15];
            acc0 = __builtin_amdgcn_mfma_f64_16x16x4f64(a0, b, acc0, 0, 0, 0);
            acc1 = __builtin_amdgcn_mfma_f64_16x16x4f64(a1, b, acc1, 0, 0, 0);
        }
        cur ^= 1;
        // no second barrier needed: writes to this buf recur 2 iters later,
        // separated from these reads by the next iteration's barrier.
    }

    // store C[n][tau] -> I0T[tau*4096 + n] as fp32, probed (row,col) per reg
#pragma unroll
    for (int r = 0; r < 4; ++r) {
        const int tcol = tau0 + wid * 16 + colr[r];
        if (tcol < T_STEPS) {
            I0T[(size_t)tcol * N0 + n0 + rowr[r]]      = (float)acc0[r];
            I0T[(size_t)tcol * N0 + n0 + 16 + rowr[r]] = (float)acc1[r];
        }
    }
}

// ============ Kernel 2: layer-0 LIF scan -> bitpacked S0 (unrolled x8) ============
__global__ void lif0(const float* __restrict__ I0T, uint32_t* __restrict__ S0bits) {
#pragma clang fp contract(off)
    const int n = blockIdx.x * 256 + threadIdx.x;   // 0..4095
    float v = 0.0f;
    uint32_t word = 0;
    int t = 0;
    for (; t + 8 <= T_STEPS; t += 8) {
        float I[8];
#pragma unroll
        for (int u = 0; u < 8; ++u) I[u] = I0T[(size_t)(t + u) * N0 + n];
#pragma unroll
        for (int u = 0; u < 8; ++u) {
            const int tt = t + u;
            float a = v * 0.9f;        // separate rounding (match jnp)
            v = a + I[u];
            if (v >= 1.0f) { word |= (1u << (tt & 31)); v = 0.0f; }
            if ((tt & 31) == 31) { S0bits[n * 20 + (tt >> 5)] = word; word = 0; }
        }
    }
    for (; t < T_STEPS; ++t) {
        float I = I0T[(size_t)t * N0 + n];
        float a = v * 0.9f;
        v = a + I;
        if (v >= 1.0f) { word |= (1u << (t & 31)); v = 0.0f; }
        if ((t & 31) == 31) { S0bits[n * 20 + (t >> 5)] = word; word = 0; }
    }
    S0bits[n * 20 + (T_STEPS >> 5)] = word;  // flush bits 576..598
}

// ============ Kernel 3: I1[j][t] = sum_i W1[j,i]*S0[i, t-d(j,i)] ============
// word(t+256) = word(t)+8, word(t+512) = word(t)+16, same bit position.
__global__ __launch_bounds__(256) void gather_i1(const float* __restrict__ W1,
                                                 const int* __restrict__ delays,
                                                 const uint32_t* __restrict__ S0bits,
                                                 float* __restrict__ I1) {
    __shared__ double  wl[N0];   // 32 KB
    __shared__ uint8_t dl[N0];   // 4 KB
    const int j   = blockIdx.x;
    const int tid = threadIdx.x;
    for (int q = tid; q < N0 / 4; q += 256) {
        const float4 w4 = *reinterpret_cast<const float4*>(&W1[(size_t)j * N0 + 4 * q]);
        wl[4 * q + 0] = (double)w4.x; wl[4 * q + 1] = (double)w4.y;
        wl[4 * q + 2] = (double)w4.z; wl[4 * q + 3] = (double)w4.w;
        const int4 dv = *reinterpret_cast<const int4*>(&delays[(size_t)j * N0 + 4 * q]);
        dl[4 * q + 0] = (uint8_t)dv.x; dl[4 * q + 1] = (uint8_t)dv.y;
        dl[4 * q + 2] = (uint8_t)dv.z; dl[4 * q + 3] = (uint8_t)dv.w;
    }
    __syncthreads();
    const int t0 = tid;
    const bool has2 = (t0 + 512 < T_STEPS);
    double a0 = 0.0, a1 = 0.0, a2 = 0.0;
#pragma unroll 2
    for (int i = 0; i < N0; ++i) {
        const int d = (int)dl[i];
        const double w = wl[i];
        const uint32_t* row = S0bits + i * 20;
        const int s   = t0 - d;          // in [-15, 255]
        const int w0  = s >> 5;          // arithmetic shift: -1 when s<0
        const int bit = s & 31;          // same bit for all three segments
        const uint32_t r1 = row[w0 + 8];
        const uint32_t r0 = (s >= 0) ? row[w0] : 0u;       // w0=-1 read stays in ws
        const uint32_t r2 = has2 ? row[w0 + 16] : 0u;
        if ((r0 >> bit) & 1u) a0 += w;
        if ((r1 >> bit) & 1u) a1 += w;
        if ((r2 >> bit) & 1u) a2 += w;
    }
    I1[(size_t)j * T_RAW + t0]       = (float)a0;
    I1[(size_t)j * T_RAW + t0 + 256] = (float)a1;
    if (has2) I1[(size_t)j * T_RAW + t0 + 512] = (float)a2;
}

// ============ Kernel 4: layer-1 LIF scan -> bitpacked S1 (unrolled x8) ============
__global__ void lif1(const float* __restrict__ I1, uint32_t* __restrict__ S1bits) {
#pragma clang fp contract(off)
    const int j = blockIdx.x * 256 + threadIdx.x;   // 0..1023
    float v = 0.0f;
    uint32_t word = 0;
    int t = 0;
    for (; t + 8 <= T_STEPS; t += 8) {
        float I[8];
#pragma unroll
        for (int u = 0; u < 8; ++u) I[u] = I1[(size_t)j * T_RAW + t + u];
#pragma unroll
        for (int u = 0; u < 8; ++u) {
            const int tt = t + u;
            float a = v * 0.9f;
            v = a + I[u];
            if (v >= 1.0f) { word |= (1u << (tt & 31)); v = 0.0f; }
            if ((tt & 31) == 31) { S1bits[j * 20 + (tt >> 5)] = word; word = 0; }
        }
    }
    for (; t < T_STEPS; ++t) {
        float I = I1[(size_t)j * T_RAW + t];
        float a = v * 0.9f;
        v = a + I;
        if (v >= 1.0f) { word |= (1u << (t & 31)); v = 0.0f; }
        if ((t & 31) == 31) { S1bits[j * 20 + (t >> 5)] = word; word = 0; }
    }
    S1bits[j * 20 + (T_STEPS >> 5)] = word;
}

// ============ Kernel 5: expand bits -> fp32 outputs (S0.T, S1.T) ============
__global__ void expand_out(const uint32_t* __restrict__ S0bits,
                           const uint32_t* __restrict__ S1bits,
                           float* __restrict__ out) {
    const int t = blockIdx.x * 256 + threadIdx.x;
    if (t >= T_STEPS) return;
    const int row = blockIdx.y;
    if (row < N0) {
        uint32_t b = (S0bits[row * 20 + (t >> 5)] >> (t & 31)) & 1u;
        out[(size_t)row * T_STEPS + t] = (float)b;
    } else {
        const int jj = row - N0;
        uint32_t b = (S1bits[jj * 20 + (t >> 5)] >> (t & 31)) & 1u;
        out[(size_t)N0 * T_STEPS + (size_t)jj * T_STEPS + t] = (float)b;
    }
}

extern "C" void kernel_launch(void* const* d_in, const int* in_sizes, int n_in,
                              void* d_out, int out_size, void* d_ws, size_t ws_size,
                              hipStream_t stream) {
    const float* stim   = (const float*)d_in[0];   // 128*128*600
    const float* W0     = (const float*)d_in[1];   // 4096*16384
    const float* W1     = (const float*)d_in[2];   // 1024*4096
    const int*   delays = (const int*)d_in[3];     // 1024*4096

    char* ws = (char*)d_ws;
    float*    I0T  = (float*)(ws + OFF_I0T);
    uint32_t* S0b  = (uint32_t*)(ws + OFF_S0B);
    float*    I1   = (float*)(ws + OFF_I1);
    uint32_t* S1b  = (uint32_t*)(ws + OFF_S1B);
    float*    out  = (float*)d_out;

    hipLaunchKernelGGL(gemm_i0_mfma, dim3(10, 128), dim3(256), 0, stream, W0, stim, I0T);
    hipLaunchKernelGGL(lif0,         dim3(16),      dim3(256), 0, stream, I0T, S0b);
    hipLaunchKernelGGL(gather_i1,    dim3(1024),    dim3(256), 0, stream, W1, delays, S0b, I1);
    hipLaunchKernelGGL(lif1,         dim3(4),       dim3(256), 0, stream, I1, S1b);
    hipLaunchKernelGGL(expand_out,   dim3(3, N0 + N1), dim3(256), 0, stream, S0b, S1b, out);
}

// Round 5
// 2715.640 us; speedup vs baseline: 1.8390x; 1.2583x over previous
//
#include <hip/hip_runtime.h>
#include <stdint.h>

#define T_STEPS 599   // T-1 scan steps (x[1:])
#define T_RAW   600
#define NIN     16384
#define N0      4096
#define N1      1024

typedef double d4 __attribute__((ext_vector_type(4)));

// ---- workspace layout (bytes) ----
static const size_t OFF_I0T = 0;
static const size_t SZ_I0T  = (size_t)T_STEPS * N0 * 4;      // 9,814,016
static const size_t OFF_S0B = OFF_I0T + SZ_I0T;
static const size_t SZ_S0B  = (size_t)N0 * 20 * 4;           // 327,680
static const size_t OFF_I1  = OFF_S0B + SZ_S0B;
static const size_t SZ_I1   = (size_t)N1 * T_RAW * 4;        // 2,457,600
static const size_t OFF_S1B = OFF_I1 + SZ_I1;                // total ~12.1 MiB

// ============ Kernel 1: I0 = W0 @ X via fp64 MFMA, dbuf BK=32 ============
// C[n][tau]: M=4096, N=599, K=16384. Block tile 32(M) x 64(N), 4 waves each
// own a 32x16 tau-slab. K-chunk 32, double-buffered fp32 LDS (26.6 KB).
// One barrier per chunk: ds_write(regs)->barrier->issue next loads->MFMA.
// At the barrier vmcnt is already 0 (loads consumed by ds_write) and
// lgkmcnt(0) makes prior-chunk LDS reads complete -> single barrier is
// race-free. NO lambdas / NO register arrays (R4 scratch regression).
__global__ __launch_bounds__(256) void gemm_i0_mfma(const float* __restrict__ W0,
                                                    const float* __restrict__ stim,
                                                    float* __restrict__ I0T) {
    __shared__ float As0[32 * 36], As1[32 * 36];   // [n-row][k], pad 36
    __shared__ float Bs0[32 * 68], Bs1[32 * 68];   // [k-row][tau], pad 68
    const int tid  = threadIdx.x;
    const int lane = tid & 63;
    const int wid  = tid >> 6;          // wave id 0..3 -> 16-wide tau slab
    const int n0   = blockIdx.y * 32;
    const int tau0 = blockIdx.x * 64;
    const int r15  = lane & 15;
    const int c    = lane >> 4;         // k-phase 0..3

    // ---- probe the C/D layout of v_mfma_f64_16x16x4f64 (proven R3) ----
    d4 zero = {0.0, 0.0, 0.0, 0.0};
    const double ap1 = (c == 0) ? 1.0 : 0.0;
    const double bp1 = (c == 0) ? (double)r15 : 0.0;
    d4 pcol = __builtin_amdgcn_mfma_f64_16x16x4f64(ap1, bp1, zero, 0, 0, 0);
    const double ap2 = (c == 0) ? (double)r15 : 0.0;
    const double bp2 = (c == 0) ? 1.0 : 0.0;
    d4 prow = __builtin_amdgcn_mfma_f64_16x16x4f64(ap2, bp2, zero, 0, 0, 0);
    int rowr[4], colr[4];
#pragma unroll
    for (int r = 0; r < 4; ++r) {
        int cc = (int)pcol[r]; cc = cc < 0 ? 0 : (cc > 15 ? 15 : cc);
        int rw = (int)prow[r]; rw = rw < 0 ? 0 : (rw > 15 ? 15 : rw);
        colr[r] = cc; rowr[r] = rw;
    }

    // ---- staging thread mapping ----
    // A tile 32x32: 1 float4/thread. row ar = tid>>3, k-col ac4 = (tid&7)*4
    const int ar  = tid >> 3;
    const int ac4 = (tid & 7) * 4;
    // B tile 32(k)x64(tau): 2 float4/thread. rows br, br+16; col bc4
    const int br  = tid >> 4;           // 0..15
    const int bc4 = (tid & 15) * 4;
    const int t0g = tau0 + bc4;
    const bool fastB = (tau0 + 68) <= T_RAW;   // blocks 0..8 fast, block 9 guarded

    const float* aP  = W0 + (size_t)(n0 + ar) * NIN + ac4;
    const float* bP0 = stim + (size_t)br * T_RAW + t0g;
    const float* bP1 = stim + (size_t)(br + 16) * T_RAW + t0g;

    // named staging registers (NO arrays)
    float4 aR, bRa, bRb;

    // ---- prologue: load chunk 0 ----
    aR = *reinterpret_cast<const float4*>(aP);
    if (fastB) {
        float4 f0 = *reinterpret_cast<const float4*>(bP0);
        float  e0 = bP0[4];
        bRa.x = f0.y; bRa.y = f0.z; bRa.z = f0.w; bRa.w = e0;
        float4 f1 = *reinterpret_cast<const float4*>(bP1);
        float  e1 = bP1[4];
        bRb.x = f1.y; bRb.y = f1.z; bRb.z = f1.w; bRb.w = e1;
    } else {
        bRa.x = (t0g + 0 < T_STEPS) ? bP0[1] : 0.0f;
        bRa.y = (t0g + 1 < T_STEPS) ? bP0[2] : 0.0f;
        bRa.z = (t0g + 2 < T_STEPS) ? bP0[3] : 0.0f;
        bRa.w = (t0g + 3 < T_STEPS) ? bP0[4] : 0.0f;
        bRb.x = (t0g + 0 < T_STEPS) ? bP1[1] : 0.0f;
        bRb.y = (t0g + 1 < T_STEPS) ? bP1[2] : 0.0f;
        bRb.z = (t0g + 2 < T_STEPS) ? bP1[3] : 0.0f;
        bRb.w = (t0g + 3 < T_STEPS) ? bP1[4] : 0.0f;
    }
    aP += 32; bP0 += 32 * T_RAW; bP1 += 32 * T_RAW;

    d4 acc0 = {0.0, 0.0, 0.0, 0.0};    // C rows n0..n0+15
    d4 acc1 = {0.0, 0.0, 0.0, 0.0};    // C rows n0+16..n0+31

#define STAGE_WRITE(AS, BS)                                               \
    *reinterpret_cast<float4*>(&AS[ar * 36 + ac4]) = aR;                  \
    *reinterpret_cast<float4*>(&BS[br * 68 + bc4]) = bRa;                 \
    *reinterpret_cast<float4*>(&BS[(br + 16) * 68 + bc4]) = bRb;

#define LOAD_NEXT()                                                       \
    aR = *reinterpret_cast<const float4*>(aP);                            \
    if (fastB) {                                                          \
        float4 f0 = *reinterpret_cast<const float4*>(bP0);                \
        float  e0 = bP0[4];                                               \
        bRa.x = f0.y; bRa.y = f0.z; bRa.z = f0.w; bRa.w = e0;             \
        float4 f1 = *reinterpret_cast<const float4*>(bP1);                \
        float  e1 = bP1[4];                                               \
        bRb.x = f1.y; bRb.y = f1.z; bRb.z = f1.w; bRb.w = e1;             \
    } else {                                                              \
        bRa.x = (t0g + 0 < T_STEPS) ? bP0[1] : 0.0f;                      \
        bRa.y = (t0g + 1 < T_STEPS) ? bP0[2] : 0.0f;                      \
        bRa.z = (t0g + 2 < T_STEPS) ? bP0[3] : 0.0f;                      \
        bRa.w = (t0g + 3 < T_STEPS) ? bP0[4] : 0.0f;                      \
        bRb.x = (t0g + 0 < T_STEPS) ? bP1[1] : 0.0f;                      \
        bRb.y = (t0g + 1 < T_STEPS) ? bP1[2] : 0.0f;                      \
        bRb.z = (t0g + 2 < T_STEPS) ? bP1[3] : 0.0f;                      \
        bRb.w = (t0g + 3 < T_STEPS) ? bP1[4] : 0.0f;                      \
    }                                                                     \
    aP += 32; bP0 += 32 * T_RAW; bP1 += 32 * T_RAW;

#define MFMA_PHASE(AS, BS)                                                \
    _Pragma("unroll")                                                     \
    for (int s = 0; s < 8; ++s) {                                         \
        const int k = 4 * s + c;                                          \
        const double a0 = (double)AS[r15 * 36 + k];                       \
        const double a1 = (double)AS[(16 + r15) * 36 + k];                \
        const double b  = (double)BS[k * 68 + wid * 16 + r15];            \
        acc0 = __builtin_amdgcn_mfma_f64_16x16x4f64(a0, b, acc0, 0, 0, 0);\
        acc1 = __builtin_amdgcn_mfma_f64_16x16x4f64(a1, b, acc1, 0, 0, 0);\
    }

    // 512 chunks of BK=32, unrolled x2 (compile-time buffer select)
    for (int chp = 0; chp < 256; ++chp) {
        // phase 0: buffer 0; next chunk index 2*chp+1 (always < 512)
        STAGE_WRITE(As0, Bs0);
        __syncthreads();
        LOAD_NEXT();
        MFMA_PHASE(As0, Bs0);
        // phase 1: buffer 1; next chunk index 2*chp+2 (guard last)
        STAGE_WRITE(As1, Bs1);
        __syncthreads();
        if (chp + 1 < 256) { LOAD_NEXT(); }
        MFMA_PHASE(As1, Bs1);
    }
#undef STAGE_WRITE
#undef LOAD_NEXT
#undef MFMA_PHASE

    // store C[n][tau] -> I0T[tau*4096 + n] as fp32, probed (row,col) per reg
#pragma unroll
    for (int r = 0; r < 4; ++r) {
        const int tcol = tau0 + wid * 16 + colr[r];
        if (tcol < T_STEPS) {
            I0T[(size_t)tcol * N0 + n0 + rowr[r]]      = (float)acc0[r];
            I0T[(size_t)tcol * N0 + n0 + 16 + rowr[r]] = (float)acc1[r];
        }
    }
}

// ============ Kernel 2: layer-0 LIF scan -> bitpacked S0 (unrolled x8) ============
__global__ void lif0(const float* __restrict__ I0T, uint32_t* __restrict__ S0bits) {
#pragma clang fp contract(off)
    const int n = blockIdx.x * 256 + threadIdx.x;   // 0..4095
    float v = 0.0f;
    uint32_t word = 0;
    int t = 0;
    for (; t + 8 <= T_STEPS; t += 8) {
        float I[8];
#pragma unroll
        for (int u = 0; u < 8; ++u) I[u] = I0T[(size_t)(t + u) * N0 + n];
#pragma unroll
        for (int u = 0; u < 8; ++u) {
            const int tt = t + u;
            float a = v * 0.9f;        // separate rounding (match jnp)
            v = a + I[u];
            if (v >= 1.0f) { word |= (1u << (tt & 31)); v = 0.0f; }
            if ((tt & 31) == 31) { S0bits[n * 20 + (tt >> 5)] = word; word = 0; }
        }
    }
    for (; t < T_STEPS; ++t) {
        float I = I0T[(size_t)t * N0 + n];
        float a = v * 0.9f;
        v = a + I;
        if (v >= 1.0f) { word |= (1u << (t & 31)); v = 0.0f; }
        if ((t & 31) == 31) { S0bits[n * 20 + (t >> 5)] = word; word = 0; }
    }
    S0bits[n * 20 + (T_STEPS >> 5)] = word;  // flush bits 576..598
}

// ============ Kernel 3: I1[j][t] = sum_i W1[j,i]*S0[i, t-d(j,i)] ============
__global__ __launch_bounds__(256) void gather_i1(const float* __restrict__ W1,
                                                 const int* __restrict__ delays,
                                                 const uint32_t* __restrict__ S0bits,
                                                 float* __restrict__ I1) {
    __shared__ double  wl[N0];   // 32 KB
    __shared__ uint8_t dl[N0];   // 4 KB
    const int j   = blockIdx.x;
    const int tid = threadIdx.x;
    for (int q = tid; q < N0 / 4; q += 256) {
        const float4 w4 = *reinterpret_cast<const float4*>(&W1[(size_t)j * N0 + 4 * q]);
        wl[4 * q + 0] = (double)w4.x; wl[4 * q + 1] = (double)w4.y;
        wl[4 * q + 2] = (double)w4.z; wl[4 * q + 3] = (double)w4.w;
        const int4 dv = *reinterpret_cast<const int4*>(&delays[(size_t)j * N0 + 4 * q]);
        dl[4 * q + 0] = (uint8_t)dv.x; dl[4 * q + 1] = (uint8_t)dv.y;
        dl[4 * q + 2] = (uint8_t)dv.z; dl[4 * q + 3] = (uint8_t)dv.w;
    }
    __syncthreads();
    const int t0 = tid;
    const bool has2 = (t0 + 512 < T_STEPS);
    double a0 = 0.0, a1 = 0.0, a2 = 0.0;
#pragma unroll 2
    for (int i = 0; i < N0; ++i) {
        const int d = (int)dl[i];
        const double w = wl[i];
        const uint32_t* row = S0bits + i * 20;
        const int s   = t0 - d;          // in [-15, 255]
        const int w0  = s >> 5;          // arithmetic shift: -1 when s<0
        const int bit = s & 31;          // same bit for all three segments
        const uint32_t r1 = row[w0 + 8];
        const uint32_t r0 = (s >= 0) ? row[w0] : 0u;
        const uint32_t r2 = has2 ? row[w0 + 16] : 0u;
        if ((r0 >> bit) & 1u) a0 += w;
        if ((r1 >> bit) & 1u) a1 += w;
        if ((r2 >> bit) & 1u) a2 += w;
    }
    I1[(size_t)j * T_RAW + t0]       = (float)a0;
    I1[(size_t)j * T_RAW + t0 + 256] = (float)a1;
    if (has2) I1[(size_t)j * T_RAW + t0 + 512] = (float)a2;
}

// ============ Kernel 4: layer-1 LIF scan -> bitpacked S1 (unrolled x8) ============
__global__ void lif1(const float* __restrict__ I1, uint32_t* __restrict__ S1bits) {
#pragma clang fp contract(off)
    const int j = blockIdx.x * 256 + threadIdx.x;   // 0..1023
    float v = 0.0f;
    uint32_t word = 0;
    int t = 0;
    for (; t + 8 <= T_STEPS; t += 8) {
        float I[8];
#pragma unroll
        for (int u = 0; u < 8; ++u) I[u] = I1[(size_t)j * T_RAW + t + u];
#pragma unroll
        for (int u = 0; u < 8; ++u) {
            const int tt = t + u;
            float a = v * 0.9f;
            v = a + I[u];
            if (v >= 1.0f) { word |= (1u << (tt & 31)); v = 0.0f; }
            if ((tt & 31) == 31) { S1bits[j * 20 + (tt >> 5)] = word; word = 0; }
        }
    }
    for (; t < T_STEPS; ++t) {
        float I = I1[(size_t)j * T_RAW + t];
        float a = v * 0.9f;
        v = a + I;
        if (v >= 1.0f) { word |= (1u << (t & 31)); v = 0.0f; }
        if ((t & 31) == 31) { S1bits[j * 20 + (t >> 5)] = word; word = 0; }
    }
    S1bits[j * 20 + (T_STEPS >> 5)] = word;
}

// ============ Kernel 5: expand bits -> fp32 outputs (S0.T, S1.T) ============
__global__ void expand_out(const uint32_t* __restrict__ S0bits,
                           const uint32_t* __restrict__ S1bits,
                           float* __restrict__ out) {
    const int t = blockIdx.x * 256 + threadIdx.x;
    if (t >= T_STEPS) return;
    const int row = blockIdx.y;
    if (row < N0) {
        uint32_t b = (S0bits[row * 20 + (t >> 5)] >> (t & 31)) & 1u;
        out[(size_t)row * T_STEPS + t] = (float)b;
    } else {
        const int jj = row - N0;
        uint32_t b = (S1bits[jj * 20 + (t >> 5)] >> (t & 31)) & 1u;
        out[(size_t)N0 * T_STEPS + (size_t)jj * T_STEPS + t] = (float)b;
    }
}

extern "C" void kernel_launch(void* const* d_in, const int* in_sizes, int n_in,
                              void* d_out, int out_size, void* d_ws, size_t ws_size,
                              hipStream_t stream) {
    const float* stim   = (const float*)d_in[0];   // 128*128*600
    const float* W0     = (const float*)d_in[1];   // 4096*16384
    const float* W1     = (const float*)d_in[2];   // 1024*4096
    const int*   delays = (const int*)d_in[3];     // 1024*4096

    char* ws = (char*)d_ws;
    float*    I0T  = (float*)(ws + OFF_I0T);
    uint32_t* S0b  = (uint32_t*)(ws + OFF_S0B);
    float*    I1   = (float*)(ws + OFF_I1);
    uint32_t* S1b  = (uint32_t*)(ws + OFF_S1B);
    float*    out  = (float*)d_out;

    hipLaunchKernelGGL(gemm_i0_mfma, dim3(10, 128), dim3(256), 0, stream, W0, stim, I0T);
    hipLaunchKernelGGL(lif0,         dim3(16),      dim3(256), 0, stream, I0T, S0b);
    hipLaunchKernelGGL(gather_i1,    dim3(1024),    dim3(256), 0, stream, W1, delays, S0b, I1);
    hipLaunchKernelGGL(lif1,         dim3(4),       dim3(256), 0, stream, I1, S1b);
    hipLaunchKernelGGL(expand_out,   dim3(3, N0 + N1), dim3(256), 0, stream, S0b, S1b, out);
}

// Round 6
// 2485.103 us; speedup vs baseline: 2.0096x; 1.0928x over previous
//
#include <hip/hip_runtime.h>
#include <stdint.h>

#define T_STEPS 599   // T-1 scan steps (x[1:])
#define T_RAW   600
#define NIN     16384
#define N0      4096
#define N1      1024
#define S0W     24    // padded words per S0 row: [pad0][19 spike words][4 zero]

typedef double d4 __attribute__((ext_vector_type(4)));

// ---- workspace layout (bytes) ----
static const size_t OFF_I0T = 0;
static const size_t SZ_I0T  = (size_t)T_STEPS * N0 * 4;      // 9,814,016
static const size_t OFF_S0B = OFF_I0T + SZ_I0T;
static const size_t SZ_S0B  = (size_t)N0 * S0W * 4;          // 393,216
static const size_t OFF_I1  = OFF_S0B + SZ_S0B;
static const size_t SZ_I1   = (size_t)N1 * T_RAW * 4;        // 2,457,600
static const size_t OFF_S1B = OFF_I1 + SZ_I1;                // total ~12.2 MiB

// ============ Kernel 1: I0 = W0 @ X via fp64 MFMA, dbuf BK=32, XCD swizzle ====
// Grid 1280 (1-D). flat -> xcd = flat&7, idx = xcd*160 + flat>>3; nB = idx/10,
// tB = idx%10: each XCD owns 16 n-groups x all 10 tau-twins -> the 10 blocks
// sharing the same W0 rows are co-resident on ONE XCD's L2 (T1; bijective,
// 1280%8==0). Pipeline per chunk (proven R5): ds_write -> barrier (vmcnt
// already 0) -> issue next loads -> MFMA. No lambdas / no reg arrays.
__global__ __launch_bounds__(256) void gemm_i0_mfma(const float* __restrict__ W0,
                                                    const float* __restrict__ stim,
                                                    float* __restrict__ I0T) {
    __shared__ float As0[32 * 36], As1[32 * 36];   // [n-row][k], pad 36
    __shared__ float Bs0[32 * 68], Bs1[32 * 68];   // [k-row][tau], pad 68
    const int tid  = threadIdx.x;
    const int lane = tid & 63;
    const int wid  = tid >> 6;          // wave id 0..3 -> 16-wide tau slab
    // XCD-chunked bijective swizzle
    const int flat = blockIdx.x;
    const int idx  = (flat & 7) * 160 + (flat >> 3);
    const int n0   = (idx / 10) * 32;
    const int tau0 = (idx % 10) * 64;
    const int r15  = lane & 15;
    const int c    = lane >> 4;         // k-phase 0..3

    // ---- probe the C/D layout of v_mfma_f64_16x16x4f64 (proven R3) ----
    d4 zero = {0.0, 0.0, 0.0, 0.0};
    const double ap1 = (c == 0) ? 1.0 : 0.0;
    const double bp1 = (c == 0) ? (double)r15 : 0.0;
    d4 pcol = __builtin_amdgcn_mfma_f64_16x16x4f64(ap1, bp1, zero, 0, 0, 0);
    const double ap2 = (c == 0) ? (double)r15 : 0.0;
    const double bp2 = (c == 0) ? 1.0 : 0.0;
    d4 prow = __builtin_amdgcn_mfma_f64_16x16x4f64(ap2, bp2, zero, 0, 0, 0);
    int rowr[4], colr[4];
#pragma unroll
    for (int r = 0; r < 4; ++r) {
        int cc = (int)pcol[r]; cc = cc < 0 ? 0 : (cc > 15 ? 15 : cc);
        int rw = (int)prow[r]; rw = rw < 0 ? 0 : (rw > 15 ? 15 : rw);
        colr[r] = cc; rowr[r] = rw;
    }

    // ---- staging thread mapping ----
    const int ar  = tid >> 3;           // A row 0..31
    const int ac4 = (tid & 7) * 4;      // A k-col
    const int br  = tid >> 4;           // B k-row 0..15 (and +16)
    const int bc4 = (tid & 15) * 4;     // B tau-col
    const int t0g = tau0 + bc4;
    const bool fastB = (tau0 + 68) <= T_RAW;   // tau-blocks 0..8 fast, 9 guarded

    const float* aP  = W0 + (size_t)(n0 + ar) * NIN + ac4;
    const float* bP0 = stim + (size_t)br * T_RAW + t0g;
    const float* bP1 = stim + (size_t)(br + 16) * T_RAW + t0g;

    float4 aR, bRa, bRb;                // named staging regs (NO arrays)

    // ---- prologue: load chunk 0 ----
    aR = *reinterpret_cast<const float4*>(aP);
    if (fastB) {
        float4 f0 = *reinterpret_cast<const float4*>(bP0);
        float  e0 = bP0[4];
        bRa.x = f0.y; bRa.y = f0.z; bRa.z = f0.w; bRa.w = e0;
        float4 f1 = *reinterpret_cast<const float4*>(bP1);
        float  e1 = bP1[4];
        bRb.x = f1.y; bRb.y = f1.z; bRb.z = f1.w; bRb.w = e1;
    } else {
        bRa.x = (t0g + 0 < T_STEPS) ? bP0[1] : 0.0f;
        bRa.y = (t0g + 1 < T_STEPS) ? bP0[2] : 0.0f;
        bRa.z = (t0g + 2 < T_STEPS) ? bP0[3] : 0.0f;
        bRa.w = (t0g + 3 < T_STEPS) ? bP0[4] : 0.0f;
        bRb.x = (t0g + 0 < T_STEPS) ? bP1[1] : 0.0f;
        bRb.y = (t0g + 1 < T_STEPS) ? bP1[2] : 0.0f;
        bRb.z = (t0g + 2 < T_STEPS) ? bP1[3] : 0.0f;
        bRb.w = (t0g + 3 < T_STEPS) ? bP1[4] : 0.0f;
    }
    aP += 32; bP0 += 32 * T_RAW; bP1 += 32 * T_RAW;

    d4 acc0 = {0.0, 0.0, 0.0, 0.0};
    d4 acc1 = {0.0, 0.0, 0.0, 0.0};

#define STAGE_WRITE(AS, BS)                                               \
    *reinterpret_cast<float4*>(&AS[ar * 36 + ac4]) = aR;                  \
    *reinterpret_cast<float4*>(&BS[br * 68 + bc4]) = bRa;                 \
    *reinterpret_cast<float4*>(&BS[(br + 16) * 68 + bc4]) = bRb;

#define LOAD_NEXT()                                                       \
    aR = *reinterpret_cast<const float4*>(aP);                            \
    if (fastB) {                                                          \
        float4 f0 = *reinterpret_cast<const float4*>(bP0);                \
        float  e0 = bP0[4];                                               \
        bRa.x = f0.y; bRa.y = f0.z; bRa.z = f0.w; bRa.w = e0;             \
        float4 f1 = *reinterpret_cast<const float4*>(bP1);                \
        float  e1 = bP1[4];                                               \
        bRb.x = f1.y; bRb.y = f1.z; bRb.z = f1.w; bRb.w = e1;             \
    } else {                                                              \
        bRa.x = (t0g + 0 < T_STEPS) ? bP0[1] : 0.0f;                      \
        bRa.y = (t0g + 1 < T_STEPS) ? bP0[2] : 0.0f;                      \
        bRa.z = (t0g + 2 < T_STEPS) ? bP0[3] : 0.0f;                      \
        bRa.w = (t0g + 3 < T_STEPS) ? bP0[4] : 0.0f;                      \
        bRb.x = (t0g + 0 < T_STEPS) ? bP1[1] : 0.0f;                      \
        bRb.y = (t0g + 1 < T_STEPS) ? bP1[2] : 0.0f;                      \
        bRb.z = (t0g + 2 < T_STEPS) ? bP1[3] : 0.0f;                      \
        bRb.w = (t0g + 3 < T_STEPS) ? bP1[4] : 0.0f;                      \
    }                                                                     \
    aP += 32; bP0 += 32 * T_RAW; bP1 += 32 * T_RAW;

#define MFMA_PHASE(AS, BS)                                                \
    __builtin_amdgcn_s_setprio(1);                                        \
    _Pragma("unroll")                                                     \
    for (int s = 0; s < 8; ++s) {                                         \
        const int k = 4 * s + c;                                          \
        const double a0 = (double)AS[r15 * 36 + k];                       \
        const double a1 = (double)AS[(16 + r15) * 36 + k];                \
        const double b  = (double)BS[k * 68 + wid * 16 + r15];            \
        acc0 = __builtin_amdgcn_mfma_f64_16x16x4f64(a0, b, acc0, 0, 0, 0);\
        acc1 = __builtin_amdgcn_mfma_f64_16x16x4f64(a1, b, acc1, 0, 0, 0);\
    }                                                                     \
    __builtin_amdgcn_s_setprio(0);

    for (int chp = 0; chp < 256; ++chp) {
        STAGE_WRITE(As0, Bs0);
        __syncthreads();
        LOAD_NEXT();
        MFMA_PHASE(As0, Bs0);
        STAGE_WRITE(As1, Bs1);
        __syncthreads();
        if (chp + 1 < 256) { LOAD_NEXT(); }
        MFMA_PHASE(As1, Bs1);
    }
#undef STAGE_WRITE
#undef LOAD_NEXT
#undef MFMA_PHASE

#pragma unroll
    for (int r = 0; r < 4; ++r) {
        const int tcol = tau0 + wid * 16 + colr[r];
        if (tcol < T_STEPS) {
            I0T[(size_t)tcol * N0 + n0 + rowr[r]]      = (float)acc0[r];
            I0T[(size_t)tcol * N0 + n0 + 16 + rowr[r]] = (float)acc1[r];
        }
    }
}

// ====== Kernel 2: layer-0 LIF scan -> padded bitpacked S0 (unrolled x8) ======
// Row layout: S0P[n*24 + 0] = 0 (pad for w0=-1), words 1..19 = spike words
// 0..18, words 20..23 = 0 (tail pad). All written every call (ws not zeroed).
__global__ void lif0(const float* __restrict__ I0T, uint32_t* __restrict__ S0P) {
#pragma clang fp contract(off)
    const int n = blockIdx.x * 256 + threadIdx.x;   // 0..4095
    uint32_t* rowp = S0P + n * S0W;
    rowp[0] = 0u;
    rowp[20] = 0u; rowp[21] = 0u; rowp[22] = 0u; rowp[23] = 0u;
    float v = 0.0f;
    uint32_t word = 0;
    int t = 0;
    for (; t + 8 <= T_STEPS; t += 8) {
        float I[8];
#pragma unroll
        for (int u = 0; u < 8; ++u) I[u] = I0T[(size_t)(t + u) * N0 + n];
#pragma unroll
        for (int u = 0; u < 8; ++u) {
            const int tt = t + u;
            float a = v * 0.9f;        // separate rounding (match jnp)
            v = a + I[u];
            if (v >= 1.0f) { word |= (1u << (tt & 31)); v = 0.0f; }
            if ((tt & 31) == 31) { rowp[1 + (tt >> 5)] = word; word = 0; }
        }
    }
    for (; t < T_STEPS; ++t) {
        float I = I0T[(size_t)t * N0 + n];
        float a = v * 0.9f;
        v = a + I;
        if (v >= 1.0f) { word |= (1u << (t & 31)); v = 0.0f; }
        if ((t & 31) == 31) { rowp[1 + (t >> 5)] = word; word = 0; }
    }
    rowp[1 + (T_STEPS >> 5)] = word;   // word 18 (bits 576..598)
}

// ====== Kernel 3: I1[j][t] = sum_i W1[j,i]*S0[i, t-d(j,i)] ======
// 128 threads x 5 t-points spaced 128 (128 % 32 == 0 -> one shared bit
// position; word indices w0+4k). Padded rows remove both boundary guards:
// idx = (t0-d)>>5 + 1 in [0,4]; reads rp0[idx + 4k] <= rp0[20] (zero pad).
__global__ __launch_bounds__(128) void gather_i1(const float* __restrict__ W1,
                                                 const int* __restrict__ delays,
                                                 const uint32_t* __restrict__ S0P,
                                                 float* __restrict__ I1) {
    __shared__ double  wl[N0];   // 32 KB
    __shared__ uint8_t dl[N0];   // 4 KB
    const int j   = blockIdx.x;
    const int tid = threadIdx.x;
    for (int q = tid; q < N0 / 4; q += 128) {
        const float4 w4 = *reinterpret_cast<const float4*>(&W1[(size_t)j * N0 + 4 * q]);
        wl[4 * q + 0] = (double)w4.x; wl[4 * q + 1] = (double)w4.y;
        wl[4 * q + 2] = (double)w4.z; wl[4 * q + 3] = (double)w4.w;
        const int4 dv = *reinterpret_cast<const int4*>(&delays[(size_t)j * N0 + 4 * q]);
        dl[4 * q + 0] = (uint8_t)dv.x; dl[4 * q + 1] = (uint8_t)dv.y;
        dl[4 * q + 2] = (uint8_t)dv.z; dl[4 * q + 3] = (uint8_t)dv.w;
    }
    __syncthreads();
    const int t0 = tid;                         // 0..127
    const bool has4 = (t0 + 512) < T_STEPS;     // t0 < 87
    double a0 = 0.0, a1 = 0.0, a2 = 0.0, a3 = 0.0, a4 = 0.0;
    const uint32_t* rp0 = S0P;                  // row base, +S0W per i
#pragma unroll 2
    for (int i = 0; i < N0; ++i) {
        const int s   = t0 - (int)dl[i];        // in [-15, 127]
        const double w = wl[i];
        const int idx = (s >> 5) + 1;           // 0..4
        const int bit = s & 31;
        const uint32_t r0 = rp0[idx];
        const uint32_t r1 = rp0[idx + 4];
        const uint32_t r2 = rp0[idx + 8];
        const uint32_t r3 = rp0[idx + 12];
        const uint32_t r4 = rp0[idx + 16];
        a0 += ((r0 >> bit) & 1u) ? w : 0.0;
        a1 += ((r1 >> bit) & 1u) ? w : 0.0;
        a2 += ((r2 >> bit) & 1u) ? w : 0.0;
        a3 += ((r3 >> bit) & 1u) ? w : 0.0;
        a4 += ((r4 >> bit) & 1u) ? w : 0.0;
        rp0 += S0W;
    }
    float* orow = I1 + (size_t)j * T_RAW + t0;
    orow[0]   = (float)a0;
    orow[128] = (float)a1;
    orow[256] = (float)a2;
    orow[384] = (float)a3;
    if (has4) orow[512] = (float)a4;
}

// ====== Kernel 4: layer-1 LIF scan -> bitpacked S1 (20 words, unrolled x8) ======
__global__ void lif1(const float* __restrict__ I1, uint32_t* __restrict__ S1bits) {
#pragma clang fp contract(off)
    const int j = blockIdx.x * 256 + threadIdx.x;   // 0..1023
    float v = 0.0f;
    uint32_t word = 0;
    int t = 0;
    for (; t + 8 <= T_STEPS; t += 8) {
        float I[8];
#pragma unroll
        for (int u = 0; u < 8; ++u) I[u] = I1[(size_t)j * T_RAW + t + u];
#pragma unroll
        for (int u = 0; u < 8; ++u) {
            const int tt = t + u;
            float a = v * 0.9f;
            v = a + I[u];
            if (v >= 1.0f) { word |= (1u << (tt & 31)); v = 0.0f; }
            if ((tt & 31) == 31) { S1bits[j * 20 + (tt >> 5)] = word; word = 0; }
        }
    }
    for (; t < T_STEPS; ++t) {
        float I = I1[(size_t)j * T_RAW + t];
        float a = v * 0.9f;
        v = a + I;
        if (v >= 1.0f) { word |= (1u << (t & 31)); v = 0.0f; }
        if ((t & 31) == 31) { S1bits[j * 20 + (t >> 5)] = word; word = 0; }
    }
    S1bits[j * 20 + (T_STEPS >> 5)] = word;
}

// ====== Kernel 5: expand bits -> fp32 outputs (S0.T, S1.T) ======
__global__ void expand_out(const uint32_t* __restrict__ S0P,
                           const uint32_t* __restrict__ S1bits,
                           float* __restrict__ out) {
    const int t = blockIdx.x * 256 + threadIdx.x;
    if (t >= T_STEPS) return;
    const int row = blockIdx.y;
    if (row < N0) {
        uint32_t b = (S0P[row * S0W + 1 + (t >> 5)] >> (t & 31)) & 1u;
        out[(size_t)row * T_STEPS + t] = (float)b;
    } else {
        const int jj = row - N0;
        uint32_t b = (S1bits[jj * 20 + (t >> 5)] >> (t & 31)) & 1u;
        out[(size_t)N0 * T_STEPS + (size_t)jj * T_STEPS + t] = (float)b;
    }
}

extern "C" void kernel_launch(void* const* d_in, const int* in_sizes, int n_in,
                              void* d_out, int out_size, void* d_ws, size_t ws_size,
                              hipStream_t stream) {
    const float* stim   = (const float*)d_in[0];   // 128*128*600
    const float* W0     = (const float*)d_in[1];   // 4096*16384
    const float* W1     = (const float*)d_in[2];   // 1024*4096
    const int*   delays = (const int*)d_in[3];     // 1024*4096

    char* ws = (char*)d_ws;
    float*    I0T  = (float*)(ws + OFF_I0T);
    uint32_t* S0b  = (uint32_t*)(ws + OFF_S0B);
    float*    I1   = (float*)(ws + OFF_I1);
    uint32_t* S1b  = (uint32_t*)(ws + OFF_S1B);
    float*    out  = (float*)d_out;

    hipLaunchKernelGGL(gemm_i0_mfma, dim3(1280),   dim3(256), 0, stream, W0, stim, I0T);
    hipLaunchKernelGGL(lif0,         dim3(16),     dim3(256), 0, stream, I0T, S0b);
    hipLaunchKernelGGL(gather_i1,    dim3(1024),   dim3(128), 0, stream, W1, delays, S0b, I1);
    hipLaunchKernelGGL(lif1,         dim3(4),      dim3(256), 0, stream, I1, S1b);
    hipLaunchKernelGGL(expand_out,   dim3(3, N0 + N1), dim3(256), 0, stream, S0b, S1b, out);
}